// Round 1
// baseline (180.008 us; speedup 1.0000x reference)
//
#include <hip/hip_runtime.h>
#include <math.h>

#define C 10
#define BLOCK 256
#define TILE_ROWS 1024
#define TILE_ELEMS (TILE_ROWS * C)   // 10240 floats = 40960 B LDS
#define PART_STRIDE 96               // 3 stats x 32 floats per block

// ---------------- Kernel 1: per-row softmax sufficient statistics ----------------

__device__ __forceinline__ void accum_row(const float* __restrict__ row,
                                          float* __restrict__ s1,
                                          float* __restrict__ s2,
                                          float* __restrict__ sl) {
  float v[C];
#pragma unroll
  for (int c = 0; c < C; c++) v[c] = row[c];
  float mx = v[0];
#pragma unroll
  for (int c = 1; c < C; c++) mx = fmaxf(mx, v[c]);
  float e[C];
  float se = 0.f;
#pragma unroll
  for (int c = 0; c < C; c++) { v[c] -= mx; e[c] = __expf(v[c]); se += e[c]; }
  float inv = 1.0f / se;
  float lse = __logf(se);
#pragma unroll
  for (int c = 0; c < C; c++) {
    float p = e[c] * inv;
    s1[c] += p;
    s2[c] += p * p;
    sl[c] += v[c] - lse;   // log p = (x - mx) - log(sum exp)
  }
}

__global__ __launch_bounds__(BLOCK) void dir_stats_kernel(
    const float* __restrict__ x, float* __restrict__ partials,
    int nrows, int ntiles, int tailStart) {
  __shared__ float tile[TILE_ELEMS];

  float s1[C], s2[C], sl[C];
#pragma unroll
  for (int c = 0; c < C; c++) { s1[c] = 0.f; s2[c] = 0.f; sl[c] = 0.f; }

  const int tid = threadIdx.x;

  for (int t = blockIdx.x; t < ntiles; t += gridDim.x) {
    // coalesced float4 stage: 2560 float4 per tile, 10 per thread
    const float4* __restrict__ src = (const float4*)(x + (size_t)t * TILE_ELEMS);
    float4* dst = (float4*)tile;
#pragma unroll
    for (int i = 0; i < TILE_ELEMS / 4 / BLOCK; i++)
      dst[tid + i * BLOCK] = src[tid + i * BLOCK];
    __syncthreads();

#pragma unroll
    for (int r = 0; r < TILE_ROWS / BLOCK; r++) {
      const float* row = tile + (size_t)(r * BLOCK + tid) * C;
      accum_row(row, s1, s2, sl);
    }
    __syncthreads();  // tile free before next load
  }

  // tail rows (< TILE_ROWS of them), last block, direct global reads
  if (blockIdx.x == gridDim.x - 1) {
    for (int rr = tailStart + tid; rr < nrows; rr += BLOCK) {
      accum_row(x + (size_t)rr * C, s1, s2, sl);
    }
  }

  // block reduction: wave shuffle, then cross-wave via LDS (alias tile)
  const int lane = tid & 63;
  const int wave = tid >> 6;
  float* red = tile;  // red[s*128 + w*32 + c], tile is free now
#pragma unroll
  for (int c = 0; c < C; c++) {
    float v1 = s1[c], v2 = s2[c], v3 = sl[c];
#pragma unroll
    for (int off = 32; off >= 1; off >>= 1) {
      v1 += __shfl_down(v1, off);
      v2 += __shfl_down(v2, off);
      v3 += __shfl_down(v3, off);
    }
    if (lane == 0) {
      red[0 * 128 + wave * 32 + c] = v1;
      red[1 * 128 + wave * 32 + c] = v2;
      red[2 * 128 + wave * 32 + c] = v3;
    }
  }
  __syncthreads();
  if (tid < C) {
#pragma unroll
    for (int s = 0; s < 3; s++) {
      float tot = red[s * 128 + 0 * 32 + tid] + red[s * 128 + 1 * 32 + tid] +
                  red[s * 128 + 2 * 32 + tid] + red[s * 128 + 3 * 32 + tid];
      partials[(size_t)blockIdx.x * PART_STRIDE + s * 32 + tid] = tot;
    }
  }
}

// ---------------- Kernel 2: reduce partials + Newton iterations (fp64) ----------------

__device__ __forceinline__ double digamma_d(double x) {
  double r = 0.0;
  for (int i = 0; i < 128 && x < 6.0; i++) { r -= 1.0 / x; x += 1.0; }
  double xi = 1.0 / x;
  double f = xi * xi;
  double p = f * (1.0 / 12 - f * (1.0 / 120 - f * (1.0 / 252 - f * (1.0 / 240 - f * (1.0 / 132)))));
  return log(x) - 0.5 * xi - p + r;
}

__device__ __forceinline__ double trigamma_d(double x) {
  double r = 0.0;
  for (int i = 0; i < 128 && x < 6.0; i++) { r += 1.0 / (x * x); x += 1.0; }
  double xi = 1.0 / x;
  double f = xi * xi;
  return r + xi + 0.5 * f + f * xi * (1.0 / 6 - f * (1.0 / 30 - f * (1.0 / 42 - f * (1.0 / 30))));
}

__device__ __forceinline__ double wsum64(double v) {
#pragma unroll
  for (int off = 1; off < 64; off <<= 1) v += __shfl_xor(v, off);
  return v;
}

__global__ __launch_bounds__(256) void dir_newton_kernel(
    const float* __restrict__ partials, float* __restrict__ out,
    int nparts, double nrows) {
  __shared__ double red8[30][8];
  __shared__ double tot[30];
  const int tid = threadIdx.x;

  if (tid < 240) {
    int j = tid >> 3, k = tid & 7;
    int s = j / 10, c = j % 10;
    double local = 0.0;
    for (int b = k; b < nparts; b += 8)
      local += (double)partials[(size_t)b * PART_STRIDE + s * 32 + c];
    red8[j][k] = local;
  }
  __syncthreads();
  if (tid < 30) {
    double t = 0.0;
#pragma unroll
    for (int k = 0; k < 8; k++) t += red8[tid][k];
    tot[tid] = t;
  }
  __syncthreads();

  if (tid < 64) {
    const int c = tid;
    const bool act = (c < C);
    double m1 = 0.1, m2 = 0.02, lpa = -2.5;
    if (act) {
      m1 = tot[c] / nrows;
      m2 = tot[10 + c] / nrows;
      lpa = tot[20 + c] / nrows;
    }
    // method-of-moments init: a0 = m1 * mean_c((m1-m2)/(m2-m1^2))
    double ratio = act ? (m1 - m2) / (m2 - m1 * m1) : 0.0;
    double rmean = wsum64(ratio) / (double)C;
    double a = act ? m1 * rmean : 1.0;

    double diff = 1e30;
    for (int k = 0; k < 100 && diff >= 1e-3; k++) {
      double S = wsum64(act ? a : 0.0);
      double dgS = digamma_d(S);
      double tgS = trigamma_d(S);
      double g = (dgS - digamma_d(a) + lpa) * nrows;
      double q = -nrows * trigamma_d(a);
      double z = nrows * tgS;
      double num = wsum64(act ? g / q : 0.0);
      double den = 1.0 / z + wsum64(act ? 1.0 / q : 0.0);
      double b = num / den;
      double anew = a - (g - b) / q;
      diff = wsum64(act ? fabs(anew - a) : 0.0);
      if (act) a = anew;
    }
    if (act) out[c] = (float)a;
  }
}

// ---------------- launch ----------------

extern "C" void kernel_launch(void* const* d_in, const int* in_sizes, int n_in,
                              void* d_out, int out_size, void* d_ws, size_t ws_size,
                              hipStream_t stream) {
  const float* x = (const float*)d_in[0];
  const int total = in_sizes[0];
  const int nrows = total / C;
  const int ntiles = nrows / TILE_ROWS;
  const int tailStart = ntiles * TILE_ROWS;

  int grid = 1024;
  size_t need = (size_t)grid * PART_STRIDE * sizeof(float);
  if (need > ws_size) {
    grid = (int)(ws_size / (PART_STRIDE * sizeof(float)));
    if (grid < 1) grid = 1;
  }

  float* partials = (float*)d_ws;
  dir_stats_kernel<<<grid, BLOCK, 0, stream>>>(x, partials, nrows, ntiles, tailStart);
  dir_newton_kernel<<<1, 256, 0, stream>>>(partials, (float*)d_out, grid, (double)nrows);
}

// Round 2
// 162.678 us; speedup vs baseline: 1.1065x; 1.1065x over previous
//
#include <hip/hip_runtime.h>
#include <math.h>

#define C 10
#define BLOCK 256
#define NBLOCKS 1024
#define NSTATS (3 * C)   // 30 series: s1[10], s2[10], slogp[10]

// ---------------- Kernel 1: per-row softmax sufficient statistics ----------------
// Grid-stride over rows; each thread owns whole rows (5 x float2 loads, 8B-aligned
// since row stride is 40B). No LDS staging, no barriers in the hot loop.

__global__ __launch_bounds__(BLOCK) void dir_stats_kernel(
    const float* __restrict__ x, float* __restrict__ partials,
    int nrows, int nblocks) {
  const int tid = threadIdx.x;
  const int gtid = blockIdx.x * BLOCK + tid;
  const int stride = nblocks * BLOCK;

  float s1[C], s2[C], sl[C];
#pragma unroll
  for (int c = 0; c < C; c++) { s1[c] = 0.f; s2[c] = 0.f; sl[c] = 0.f; }

  for (int r = gtid; r < nrows; r += stride) {
    const float2* __restrict__ row = (const float2*)(x + (size_t)r * C);
    float2 t0 = row[0], t1 = row[1], t2 = row[2], t3 = row[3], t4 = row[4];
    float v[C];
    v[0] = t0.x; v[1] = t0.y; v[2] = t1.x; v[3] = t1.y; v[4] = t2.x;
    v[5] = t2.y; v[6] = t3.x; v[7] = t3.y; v[8] = t4.x; v[9] = t4.y;

    float mx = v[0];
#pragma unroll
    for (int c = 1; c < C; c++) mx = fmaxf(mx, v[c]);
    float e[C], se = 0.f;
#pragma unroll
    for (int c = 0; c < C; c++) { v[c] -= mx; e[c] = __expf(v[c]); se += e[c]; }
    float inv = 1.0f / se;
    float lse = __logf(se);
#pragma unroll
    for (int c = 0; c < C; c++) {
      float p = e[c] * inv;
      s1[c] += p;
      s2[c] += p * p;
      sl[c] += v[c] - lse;   // log p = (x - mx) - lse
    }
  }

  // block reduction: wave shuffles, then cross-wave via LDS
  const int lane = tid & 63;
  const int wave = tid >> 6;
  __shared__ float red[4][NSTATS];
#pragma unroll
  for (int c = 0; c < C; c++) {
    float v1 = s1[c], v2 = s2[c], v3 = sl[c];
#pragma unroll
    for (int off = 32; off >= 1; off >>= 1) {
      v1 += __shfl_down(v1, off);
      v2 += __shfl_down(v2, off);
      v3 += __shfl_down(v3, off);
    }
    if (lane == 0) {
      red[wave][c] = v1;
      red[wave][C + c] = v2;
      red[wave][2 * C + c] = v3;
    }
  }
  __syncthreads();
  if (tid < NSTATS) {
    float tot = red[0][tid] + red[1][tid] + red[2][tid] + red[3][tid];
    // SoA: series j contiguous over blocks -> coalesced reduction in kernel 2
    partials[(size_t)tid * nblocks + blockIdx.x] = tot;
  }
}

// ---------------- Kernel 2: coalesced reduce + Newton iterations (fp64) ----------------

__device__ __forceinline__ void digtri(double x, double& dg, double& tg) {
  // digamma + trigamma together, sharing the 1/x per recurrence step
  double rd = 0.0, rt = 0.0;
#pragma unroll 1
  for (int i = 0; i < 64 && x < 6.0; i++) {
    double inv = 1.0 / x;
    rd -= inv;
    rt += inv * inv;
    x += 1.0;
  }
  double xi = 1.0 / x, f = xi * xi;
  dg = log(x) - 0.5 * xi
     - f * (1.0 / 12 - f * (1.0 / 120 - f * (1.0 / 252 - f * (1.0 / 240 - f * (1.0 / 132)))))
     + rd;
  tg = rt + xi + 0.5 * f
     + f * xi * (1.0 / 6 - f * (1.0 / 30 - f * (1.0 / 42 - f * (1.0 / 30))));
}

__device__ __forceinline__ double wsum16(double v) {
  // sum across lanes 0..15 (lanes 10..15 must hold 0)
#pragma unroll
  for (int off = 1; off < 16; off <<= 1) v += __shfl_xor(v, off);
  return v;
}

__global__ __launch_bounds__(256) void dir_newton_kernel(
    const float* __restrict__ partials, float* __restrict__ out,
    int nparts, double nrows) {
  __shared__ double tot[NSTATS];
  const int tid = threadIdx.x;
  const int lane = tid & 63;
  const int wave = tid >> 6;

  // Phase A: wave w reduces series j = w, w+4, ... — fully coalesced,
  // 16 independent loads per lane kept in flight.
  for (int j = wave; j < NSTATS; j += 4) {
    double s = 0.0;
    for (int b = lane; b < nparts; b += 64)
      s += (double)partials[(size_t)j * nparts + b];
#pragma unroll
    for (int off = 32; off >= 1; off >>= 1) s += __shfl_down(s, off);
    if (lane == 0) tot[j] = s;
  }
  __syncthreads();

  // Phase B: Newton on lanes 0..15 of wave 0 (lane = channel, 10 active)
  if (tid < 16) {
    const int c = tid;
    const bool act = (c < C);
    const double n = nrows;
    double m1 = 0.0, m2 = 0.0, lpa = 0.0;
    if (act) {
      m1 = tot[c] / n;
      m2 = tot[C + c] / n;
      lpa = tot[2 * C + c] / n;
    }
    // method-of-moments init: a0 = m1 * mean_c((m1-m2)/(m2-m1^2))
    double ratio = act ? (m1 - m2) / (m2 - m1 * m1) : 0.0;
    double rmean = wsum16(ratio) / (double)C;
    double a = act ? m1 * rmean : 0.0;

    double diff = 1e30;
    for (int k = 0; k < 100 && diff >= 1e-3; k++) {
      double S = wsum16(a);          // inactive lanes hold 0
      double dgS, tgS;
      digtri(S, dgS, tgS);
      double dga = 0.0, tga = 1.0;
      if (act) digtri(a, dga, tga);
      double g = act ? (dgS - dga + lpa) * n : 0.0;
      double qinv = act ? (-1.0) / (n * tga) : 0.0;   // 1/q
      double z = n * tgS;
      double num = wsum16(g * qinv);
      double den = 1.0 / z + wsum16(qinv);
      double b = num / den;
      double anew = act ? a - (g - b) * qinv : 0.0;
      diff = wsum16(act ? fabs(anew - a) : 0.0);
      a = anew;
    }
    if (act) out[c] = (float)a;
  }
}

// ---------------- launch ----------------

extern "C" void kernel_launch(void* const* d_in, const int* in_sizes, int n_in,
                              void* d_out, int out_size, void* d_ws, size_t ws_size,
                              hipStream_t stream) {
  const float* x = (const float*)d_in[0];
  const int total = in_sizes[0];
  const int nrows = total / C;

  int grid = NBLOCKS;
  size_t need = (size_t)NSTATS * grid * sizeof(float);
  if (need > ws_size) {
    grid = (int)(ws_size / (NSTATS * sizeof(float)));
    if (grid < 1) grid = 1;
  }

  float* partials = (float*)d_ws;
  dir_stats_kernel<<<grid, BLOCK, 0, stream>>>(x, partials, nrows, grid);
  dir_newton_kernel<<<1, 256, 0, stream>>>(partials, (float*)d_out, grid, (double)nrows);
}

// Round 3
// 162.283 us; speedup vs baseline: 1.1092x; 1.0024x over previous
//
#include <hip/hip_runtime.h>
#include <math.h>

#define C 10
#define BLOCK 256
#define NBLOCKS 1024
#define TILE_ROWS 512
#define TILE_ELEMS (TILE_ROWS * C)      // 5120 floats = 20 KB LDS
#define NSTATS (3 * C)                  // 30 series

// ---------------- Kernel 1: per-row softmax sufficient statistics ----------------
// Coalesced float4 staging into LDS, then per-thread row compute from LDS.

__device__ __forceinline__ void accum_row(const float* __restrict__ row,
                                          float* __restrict__ s1,
                                          float* __restrict__ s2,
                                          float* __restrict__ sl) {
  float v[C];
#pragma unroll
  for (int c = 0; c < C; c++) v[c] = row[c];
  float mx = v[0];
#pragma unroll
  for (int c = 1; c < C; c++) mx = fmaxf(mx, v[c]);
  float e[C], se = 0.f;
#pragma unroll
  for (int c = 0; c < C; c++) { v[c] -= mx; e[c] = __expf(v[c]); se += e[c]; }
  float inv = 1.0f / se;
  float lse = __logf(se);
#pragma unroll
  for (int c = 0; c < C; c++) {
    float p = e[c] * inv;
    s1[c] = fmaf(p, 1.0f, s1[c]);
    s2[c] = fmaf(p, p, s2[c]);
    sl[c] += v[c] - lse;                // log p = (x - mx) - lse
  }
}

__global__ __launch_bounds__(BLOCK) void dir_stats_kernel(
    const float* __restrict__ x, float* __restrict__ partials,
    int nrows, int ntiles, int tailStart, int nblocks) {
  __shared__ float tile[TILE_ELEMS];
  const int tid = threadIdx.x;

  float s1[C], s2[C], sl[C];
#pragma unroll
  for (int c = 0; c < C; c++) { s1[c] = 0.f; s2[c] = 0.f; sl[c] = 0.f; }

  for (int t = blockIdx.x; t < ntiles; t += nblocks) {
    const float4* __restrict__ src = (const float4*)(x + (size_t)t * TILE_ELEMS);
    float4* dst = (float4*)tile;
#pragma unroll
    for (int i = 0; i < TILE_ELEMS / 4 / BLOCK; i++)    // 5 float4 per thread
      dst[tid + i * BLOCK] = src[tid + i * BLOCK];
    __syncthreads();

#pragma unroll
    for (int r = 0; r < TILE_ROWS / BLOCK; r++)         // 2 rows per thread
      accum_row(tile + (size_t)(r * BLOCK + tid) * C, s1, s2, sl);
    __syncthreads();
  }

  // tail rows (< TILE_ROWS), last block only, direct global reads
  if (blockIdx.x == nblocks - 1) {
    for (int rr = tailStart + tid; rr < nrows; rr += BLOCK)
      accum_row(x + (size_t)rr * C, s1, s2, sl);
  }

  // block reduction: wave shuffle, then cross-wave via LDS
  const int lane = tid & 63;
  const int wave = tid >> 6;
  __shared__ float red[4][NSTATS];
#pragma unroll
  for (int c = 0; c < C; c++) {
    float v1 = s1[c], v2 = s2[c], v3 = sl[c];
#pragma unroll
    for (int off = 32; off >= 1; off >>= 1) {
      v1 += __shfl_down(v1, off);
      v2 += __shfl_down(v2, off);
      v3 += __shfl_down(v3, off);
    }
    if (lane == 0) {
      red[wave][c] = v1;
      red[wave][C + c] = v2;
      red[wave][2 * C + c] = v3;
    }
  }
  __syncthreads();
  if (tid < NSTATS) {
    float tot = red[0][tid] + red[1][tid] + red[2][tid] + red[3][tid];
    // SoA: series j contiguous over blocks -> coalesced reduce in kernel 2
    partials[(size_t)tid * nblocks + blockIdx.x] = tot;
  }
}

// ---------------- Kernel 2: coalesced reduce + Newton iterations (fp64) ----------------

__device__ __forceinline__ void digtri(double x, double& dg, double& tg) {
  double rd = 0.0, rt = 0.0;
#pragma unroll 1
  for (int i = 0; i < 64 && x < 6.0; i++) {
    double inv = 1.0 / x;
    rd -= inv;
    rt += inv * inv;
    x += 1.0;
  }
  double xi = 1.0 / x, f = xi * xi;
  dg = log(x) - 0.5 * xi
     - f * (1.0 / 12 - f * (1.0 / 120 - f * (1.0 / 252 - f * (1.0 / 240 - f * (1.0 / 132)))))
     + rd;
  tg = rt + xi + 0.5 * f
     + f * xi * (1.0 / 6 - f * (1.0 / 30 - f * (1.0 / 42 - f * (1.0 / 30))));
}

__device__ __forceinline__ double wsum16(double v) {
#pragma unroll
  for (int off = 1; off < 16; off <<= 1) v += __shfl_xor(v, off);
  return v;
}

__global__ __launch_bounds__(256) void dir_newton_kernel(
    const float* __restrict__ partials, float* __restrict__ out,
    int nparts, double nrows) {
  __shared__ double tot[NSTATS];
  const int tid = threadIdx.x;
  const int lane = tid & 63;
  const int wave = tid >> 6;

  // Phase A: wave w reduces series j = w, w+4, ... — fully coalesced.
  for (int j = wave; j < NSTATS; j += 4) {
    double s = 0.0;
    for (int b = lane; b < nparts; b += 64)
      s += (double)partials[(size_t)j * nparts + b];
#pragma unroll
    for (int off = 32; off >= 1; off >>= 1) s += __shfl_down(s, off);
    if (lane == 0) tot[j] = s;
  }
  __syncthreads();

  // Phase B: Newton on lanes 0..15 (lane = channel, 10 active)
  if (tid < 16) {
    const int c = tid;
    const bool act = (c < C);
    const double n = nrows;
    double m1 = 0.0, m2 = 0.0, lpa = 0.0;
    if (act) {
      m1 = tot[c] / n;
      m2 = tot[C + c] / n;
      lpa = tot[2 * C + c] / n;
    }
    double ratio = act ? (m1 - m2) / (m2 - m1 * m1) : 0.0;
    double rmean = wsum16(ratio) / (double)C;
    double a = act ? m1 * rmean : 0.0;

    double diff = 1e30;
    for (int k = 0; k < 100 && diff >= 1e-3; k++) {
      double S = wsum16(a);
      double dgS, tgS;
      digtri(S, dgS, tgS);
      double dga = 0.0, tga = 1.0;
      if (act) digtri(a, dga, tga);
      double g = act ? (dgS - dga + lpa) * n : 0.0;
      double qinv = act ? (-1.0) / (n * tga) : 0.0;
      double z = n * tgS;
      double num = wsum16(g * qinv);
      double den = 1.0 / z + wsum16(qinv);
      double b = num / den;
      double anew = act ? a - (g - b) * qinv : 0.0;
      diff = wsum16(act ? fabs(anew - a) : 0.0);
      a = anew;
    }
    if (act) out[c] = (float)a;
  }
}

// ---------------- launch ----------------

extern "C" void kernel_launch(void* const* d_in, const int* in_sizes, int n_in,
                              void* d_out, int out_size, void* d_ws, size_t ws_size,
                              hipStream_t stream) {
  const float* x = (const float*)d_in[0];
  const int total = in_sizes[0];
  const int nrows = total / C;
  const int ntiles = nrows / TILE_ROWS;
  const int tailStart = ntiles * TILE_ROWS;

  int grid = NBLOCKS;
  size_t need = (size_t)NSTATS * grid * sizeof(float);
  if (need > ws_size) {
    grid = (int)(ws_size / (NSTATS * sizeof(float)));
    if (grid < 1) grid = 1;
  }

  float* partials = (float*)d_ws;
  dir_stats_kernel<<<grid, BLOCK, 0, stream>>>(x, partials, nrows, ntiles, tailStart, grid);
  dir_newton_kernel<<<1, 256, 0, stream>>>(partials, (float*)d_out, grid, (double)nrows);
}

// Round 4
// 128.261 us; speedup vs baseline: 1.4034x; 1.2653x over previous
//
#include <hip/hip_runtime.h>
#include <math.h>

#define C 10
#define BLOCK 256
#define NBLOCKS 1024
#define TILE_ROWS 512
#define TILE_ELEMS (TILE_ROWS * C)      // 5120 floats = 20 KB LDS
#define NSTATS (3 * C)                  // 30 series

// ---------------- Kernel 1: per-row softmax sufficient statistics ----------------

__device__ __forceinline__ void accum_row(const float* __restrict__ row,
                                          float* __restrict__ s1,
                                          float* __restrict__ s2,
                                          float* __restrict__ sl) {
  float v[C];
#pragma unroll
  for (int c = 0; c < C; c++) v[c] = row[c];
  float mx = v[0];
#pragma unroll
  for (int c = 1; c < C; c++) mx = fmaxf(mx, v[c]);
  float e[C], se = 0.f;
#pragma unroll
  for (int c = 0; c < C; c++) { v[c] -= mx; e[c] = __expf(v[c]); se += e[c]; }
  float inv = 1.0f / se;
  float lse = __logf(se);
#pragma unroll
  for (int c = 0; c < C; c++) {
    float p = e[c] * inv;
    s1[c] += p;
    s2[c] = fmaf(p, p, s2[c]);
    sl[c] += v[c] - lse;                // log p = (x - mx) - lse
  }
}

__global__ __launch_bounds__(BLOCK) void dir_stats_kernel(
    const float* __restrict__ x, float* __restrict__ partials,
    int nrows, int ntiles, int tailStart, int nblocks) {
  __shared__ float tile[TILE_ELEMS];
  const int tid = threadIdx.x;

  float s1[C], s2[C], sl[C];
#pragma unroll
  for (int c = 0; c < C; c++) { s1[c] = 0.f; s2[c] = 0.f; sl[c] = 0.f; }

  for (int t = blockIdx.x; t < ntiles; t += nblocks) {
    const float4* __restrict__ src = (const float4*)(x + (size_t)t * TILE_ELEMS);
    float4* dst = (float4*)tile;
#pragma unroll
    for (int i = 0; i < TILE_ELEMS / 4 / BLOCK; i++)    // 5 float4 per thread
      dst[tid + i * BLOCK] = src[tid + i * BLOCK];
    __syncthreads();

#pragma unroll
    for (int r = 0; r < TILE_ROWS / BLOCK; r++)         // 2 rows per thread
      accum_row(tile + (size_t)(r * BLOCK + tid) * C, s1, s2, sl);
    __syncthreads();
  }

  if (blockIdx.x == nblocks - 1) {
    for (int rr = tailStart + tid; rr < nrows; rr += BLOCK)
      accum_row(x + (size_t)rr * C, s1, s2, sl);
  }

  // block reduction: wave shuffle, then cross-wave via LDS
  const int lane = tid & 63;
  const int wave = tid >> 6;
  __shared__ float red[4][NSTATS];
#pragma unroll
  for (int c = 0; c < C; c++) {
    float v1 = s1[c], v2 = s2[c], v3 = sl[c];
#pragma unroll
    for (int off = 32; off >= 1; off >>= 1) {
      v1 += __shfl_down(v1, off);
      v2 += __shfl_down(v2, off);
      v3 += __shfl_down(v3, off);
    }
    if (lane == 0) {
      red[wave][c] = v1;
      red[wave][C + c] = v2;
      red[wave][2 * C + c] = v3;
    }
  }
  __syncthreads();
  if (tid < NSTATS) {
    float tot = red[0][tid] + red[1][tid] + red[2][tid] + red[3][tid];
    partials[(size_t)tid * nblocks + blockIdx.x] = tot;   // SoA over blocks
  }
}

// ---------------- Kernel 2: MLP-parallel reduce + Newton (fp64) ----------------

__device__ __forceinline__ void digtri(double x, double& dg, double& tg) {
  double rd = 0.0, rt = 0.0;
#pragma unroll 1
  for (int i = 0; i < 64 && x < 6.0; i++) {
    double inv = 1.0 / x;
    rd -= inv;
    rt += inv * inv;
    x += 1.0;
  }
  double xi = 1.0 / x, f = xi * xi;
  dg = log(x) - 0.5 * xi
     - f * (1.0 / 12 - f * (1.0 / 120 - f * (1.0 / 252 - f * (1.0 / 240 - f * (1.0 / 132)))))
     + rd;
  tg = rt + xi + 0.5 * f
     + f * xi * (1.0 / 6 - f * (1.0 / 30 - f * (1.0 / 42 - f * (1.0 / 30))));
}

__device__ __forceinline__ double wsum16(double v) {
#pragma unroll
  for (int off = 1; off < 16; off <<= 1) v += __shfl_xor(v, off);
  return v;
}

__global__ __launch_bounds__(1024) void dir_newton_kernel(
    const float* __restrict__ partials, float* __restrict__ out,
    int nparts, double nrows) {
  __shared__ double tot[NSTATS];
  const int tid = threadIdx.x;

  // Phase A: 32 threads per series (30 series -> 960 active threads).
  // Each thread sums nparts/32 elements, loads batched 8-deep for MLP.
  {
    const int j = tid >> 5;        // series
    const int k = tid & 31;        // sub-lane within series group
    double s = 0.0;
    if (j < NSTATS) {
      const float* __restrict__ base = partials + (size_t)j * nparts;
#pragma unroll 8
      for (int b = k; b < nparts; b += 32)
        s += (double)base[b];
    }
    // reduce within the 32-lane group (series never crosses a 32-lane boundary)
#pragma unroll
    for (int off = 16; off >= 1; off >>= 1) s += __shfl_xor(s, off);
    if (j < NSTATS && k == 0) tot[j] = s;
  }
  __syncthreads();

  // Phase B: Newton on lanes 0..15 (lane = channel, 10 active)
  if (tid < 16) {
    const int c = tid;
    const bool act = (c < C);
    const double n = nrows;
    double m1 = 0.0, m2 = 0.0, lpa = 0.0;
    if (act) {
      m1 = tot[c] / n;
      m2 = tot[C + c] / n;
      lpa = tot[2 * C + c] / n;
    }
    double ratio = act ? (m1 - m2) / (m2 - m1 * m1) : 0.0;
    double rmean = wsum16(ratio) / (double)C;
    double a = act ? m1 * rmean : 0.0;

    double diff = 1e30;
    for (int k = 0; k < 100 && diff >= 1e-3; k++) {
      double S = wsum16(a);
      double dgS, tgS;
      digtri(S, dgS, tgS);
      double dga = 0.0, tga = 1.0;
      if (act) digtri(a, dga, tga);
      double g = act ? (dgS - dga + lpa) * n : 0.0;
      double qinv = act ? (-1.0) / (n * tga) : 0.0;
      double z = n * tgS;
      double num = wsum16(g * qinv);
      double den = 1.0 / z + wsum16(qinv);
      double b = num / den;
      double anew = act ? a - (g - b) * qinv : 0.0;
      diff = wsum16(act ? fabs(anew - a) : 0.0);
      a = anew;
    }
    if (act) out[c] = (float)a;
  }
}

// ---------------- launch ----------------

extern "C" void kernel_launch(void* const* d_in, const int* in_sizes, int n_in,
                              void* d_out, int out_size, void* d_ws, size_t ws_size,
                              hipStream_t stream) {
  const float* x = (const float*)d_in[0];
  const int total = in_sizes[0];
  const int nrows = total / C;
  const int ntiles = nrows / TILE_ROWS;
  const int tailStart = ntiles * TILE_ROWS;

  int grid = NBLOCKS;
  size_t need = (size_t)NSTATS * grid * sizeof(float);
  if (need > ws_size) {
    grid = (int)(ws_size / (NSTATS * sizeof(float)));
    if (grid < 1) grid = 1;
  }

  float* partials = (float*)d_ws;
  dir_stats_kernel<<<grid, BLOCK, 0, stream>>>(x, partials, nrows, ntiles, tailStart, grid);
  dir_newton_kernel<<<1, 1024, 0, stream>>>(partials, (float*)d_out, grid, (double)nrows);
}